// Round 13
// baseline (223.531 us; speedup 1.0000x reference)
//
#include <hip/hip_runtime.h>

#define DEG 16
#define TT 16
#define MM 8
#define MM2 4          /* MM/2 packed pairs */
#define NNR 8          /* regular rows per lane: lane h owns neighbors [h*8, h*8+8) */

#define C_SCALE 14.426950408889634f   /* log2(e)/eps, eps=0.1 */
#define QSH 0.07537716f               /* log2(17/8)/C_SCALE: folds q/p into kernel scale */
#define GS 0.125f                     /* G = GS * u_hat . K_hat . v_hat  (= (1/17)*(17/8)) */

#define TFP_PITCH 516   /* floats per t-row of interleaved tf (512 + 4 pad) */
#define C2_STRIDE 66    /* even (8B-align for f32x2 loads); 66%32==2 -> conflict-free */
#define G0_STRIDE 9     /* 9%32 coprime -> conflict-free boundary access */

typedef float f32x2 __attribute__((ext_vector_type(2)));

static __device__ __forceinline__ f32x2 mk2(float a, float b) { f32x2 r; r.x = a; r.y = b; return r; }
static __device__ __forceinline__ f32x2 exp2_pk(f32x2 a) {
  return mk2(__builtin_amdgcn_exp2f(a.x), __builtin_amdgcn_exp2f(a.y));
}

// ---- kernel A: P = x @ tf_flat^T  [n_nodes x 128], sqn = ||x_i||^2.  2 nodes/lane ----
// tf staged interleaved by m-pairs: float idx = t*TFP_PITCH + m2*128 + k*8 + 2*dd + half,
// so one float4 read gives two f32x2 operands {row2m2[d], row2m2+1[d]}.
__global__ __launch_bounds__(256) void precomp(const float* __restrict__ x,
                                               const float* __restrict__ tf,
                                               float* __restrict__ P,
                                               float* __restrict__ sqn) {
  __shared__ float tf_i[TT * TFP_PITCH];   // ~33 KB
  const float4* tf4g = (const float4*)tf;
  for (int i = threadIdx.x; i < TT * MM * 16; i += 256) {
    int r = i >> 4, ck = i & 15;
    int tt = r >> 3, m = r & 7, m2 = m >> 1, half = m & 1;
    float4 v = tf4g[i];
    float* base = &tf_i[tt * TFP_PITCH + m2 * 128 + ck * 8 + half];
    base[0] = v.x; base[2] = v.y; base[4] = v.z; base[6] = v.w;
  }
  __syncthreads();

  int gid = blockIdx.x * 256 + (int)threadIdx.x;
  int pairI = gid >> 4, c = gid & 15;
  int n0 = pairI * 2, n1 = n0 + 1;
  const float4* xa4 = (const float4*)x + (size_t)n0 * 16;
  const float4* xb4 = (const float4*)x + (size_t)n1 * 16;
  const float* tfl = &tf_i[c * TFP_PITCH];

  f32x2 accA[MM2], accB[MM2], sq2A = mk2(0.f, 0.f), sq2B = mk2(0.f, 0.f);
#pragma unroll
  for (int m2 = 0; m2 < MM2; ++m2) { accA[m2] = mk2(0.f, 0.f); accB[m2] = mk2(0.f, 0.f); }

  for (int k = 0; k < 16; ++k) {
    float4 xa = xa4[k], xb = xb4[k];
    sq2A += mk2(xa.x, xa.y) * mk2(xa.x, xa.y) + mk2(xa.z, xa.w) * mk2(xa.z, xa.w);
    sq2B += mk2(xb.x, xb.y) * mk2(xb.x, xb.y) + mk2(xb.z, xb.w) * mk2(xb.z, xb.w);
#pragma unroll
    for (int m2 = 0; m2 < MM2; ++m2) {
      const float4* tq = (const float4*)(tfl + m2 * 128 + k * 8);
      float4 q0 = tq[0], q1 = tq[1];
      accA[m2] += (mk2(q0.x, q0.y) * xa.x + mk2(q0.z, q0.w) * xa.y)
                + (mk2(q1.x, q1.y) * xa.z + mk2(q1.z, q1.w) * xa.w);
      accB[m2] += (mk2(q0.x, q0.y) * xb.x + mk2(q0.z, q0.w) * xb.y)
                + (mk2(q1.x, q1.y) * xb.z + mk2(q1.z, q1.w) * xb.w);
    }
  }
#pragma unroll
  for (int m2 = 0; m2 < MM2; ++m2) {
    *(f32x2*)(P + (size_t)n0 * 128 + c * 8 + 2 * m2) = accA[m2];
    *(f32x2*)(P + (size_t)n1 * 128 + c * 8 + 2 * m2) = accB[m2];
  }
  if (c == 0) {
    sqn[n0] = sq2A.x + sq2A.y;
    sqn[n1] = sq2B.x + sq2B.y;
  }
}

// ---------------- kernel B: 2 lanes per (node,template) FGW problem ----------------
// q/p folded into kernel scale (QSH); g0 marginal parked in LDS across the inner
// loop (frees 8 VGPRs); reductions tree-shaped for ILP.
__global__ __launch_bounds__(256)
void ltfgw_main(const float* __restrict__ P,
                const float* __restrict__ sqn,
                const int* __restrict__ dstRow,
                const float* __restrict__ c2g,
                float* __restrict__ out) {
  __shared__ float c2_lds[TT * C2_STRIDE];
  __shared__ float g0_lds[128 * G0_STRIDE];
  for (int i = threadIdx.x; i < TT * MM * MM; i += 256) {
    int tt = i >> 6, rem = i & 63;
    c2_lds[tt * C2_STRIDE + rem] = c2g[i];
  }
  __syncthreads();

  const int tid = (int)threadIdx.x;
  const int gid = blockIdx.x * 256 + tid;
  const int t = gid & 15;
  const int h = (gid >> 4) & 1;           // half: lane pair via xor 16
  const int node = gid >> 5;
  const float hmask = (h == 0) ? 1.f : 0.f;
  const float* c2l = &c2_lds[t * C2_STRIDE];
  float* g0p = &g0_lds[((int)((tid >> 5) << 4) | (tid & 15)) * G0_STRIDE];

  const float4* Pb = (const float4*)P;
  const int* nb = dstRow + node * DEG + h * NNR;

  // ---- gather my 8 rows of P, build row-normalized kernel factor E (packed) ----
  f32x2 E2[NNR][MM2];
#pragma unroll
  for (int k = 0; k < NNR; ++k) {
    int idx = nb[k];
    float4 p0 = Pb[(size_t)idx * 32 + t * 2];
    float4 p1 = Pb[(size_t)idx * 32 + t * 2 + 1];
    float pm = fmaxf(fmaxf(fmaxf(p0.x, p0.y), fmaxf(p0.z, p0.w)),
                     fmaxf(fmaxf(p1.x, p1.y), fmaxf(p1.z, p1.w)));
    float pmc = -C_SCALE * pm;
    E2[k][0] = exp2_pk(mk2(p0.x, p0.y) * C_SCALE + pmc);
    E2[k][1] = exp2_pk(mk2(p0.z, p0.w) * C_SCALE + pmc);
    E2[k][2] = exp2_pk(mk2(p1.x, p1.y) * C_SCALE + pmc);
    E2[k][3] = exp2_pk(mk2(p1.z, p1.w) * C_SCALE + pmc);
  }
  f32x2 e0c2[MM2];
  {  // center row (lane0 keeps it; lane1 zeros, branch-free)
    float4 p0 = Pb[(size_t)node * 32 + t * 2];
    float4 p1 = Pb[(size_t)node * 32 + t * 2 + 1];
    float pm = fmaxf(fmaxf(fmaxf(p0.x, p0.y), fmaxf(p0.z, p0.w)),
                     fmaxf(fmaxf(p1.x, p1.y), fmaxf(p1.z, p1.w)));
    float pmc = -C_SCALE * pm;
    e0c2[0] = hmask * exp2_pk(mk2(p0.x, p0.y) * C_SCALE + pmc);
    e0c2[1] = hmask * exp2_pk(mk2(p0.z, p0.w) * C_SCALE + pmc);
    e0c2[2] = hmask * exp2_pk(mk2(p1.x, p1.y) * C_SCALE + pmc);
    e0c2[3] = hmask * exp2_pk(mk2(p1.z, p1.w) * C_SCALE + pmc);
  }

  // ---- fold outer-0 column cost factors (incl. 8/17 scale via QSH) ----
#pragma unroll
  for (int j2 = 0; j2 < MM2; ++j2) {
    float t0v[2], t1v[2];
#pragma unroll
    for (int half = 0; half < 2; ++half) {
      int j = 2 * j2 + half;
      float s = 0.f, cs = 0.f;
#pragma unroll
      for (int k = 0; k < MM; ++k) {
        float a = c2l[j * MM + k];
        s += a * a;
        cs += c2l[k * MM + j];
      }
      float bq = 0.125f * s;
      t0v[half] = 0.5f * (16.f / 17.f + bq) - 0.125f * cs + cs * (1.f / 136.f) + QSH;
      t1v[half] = 0.5f * (1.f / 17.f + bq) - cs * (1.f / 136.f) + QSH;
    }
    e0c2[j2] *= exp2_pk(mk2(-C_SCALE * t0v[0], -C_SCALE * t0v[1]));
    f32x2 f1 = exp2_pk(mk2(-C_SCALE * t1v[0], -C_SCALE * t1v[1]));
#pragma unroll
    for (int k = 0; k < NNR; ++k) E2[k][j2] *= f1;
  }

  // g0 (row-0 marginal) parked in LDS across inner loops
#pragma unroll
  for (int j = 0; j < MM; ++j) g0p[j] = 1.f / 136.f;

  float g0c[MM];       // current marginal: live only between inner loop and boundary
  f32x2 v2[MM2];
  float u0, ureg[NNR];

  for (int outer = 0; outer < 4; ++outer) {
#pragma unroll
    for (int j2 = 0; j2 < MM2; ++j2) v2[j2] = mk2(1.f, 1.f);
    // unnormalized stabilized Sinkhorn: u=rcp(Kv), v=rcp(K^T u); scale exact in GS
    for (int it = 0; it < 10; ++it) {
      f32x2 a01 = e0c2[0] * v2[0] + e0c2[1] * v2[1];
      f32x2 a23 = e0c2[2] * v2[2] + e0c2[3] * v2[3];
      f32x2 a = a01 + a23;
      u0 = __builtin_amdgcn_rcpf((float)h + (a.x + a.y));
#pragma unroll
      for (int k = 0; k < NNR; ++k) {
        f32x2 b01 = E2[k][0] * v2[0] + E2[k][1] * v2[1];
        f32x2 b23 = E2[k][2] * v2[2] + E2[k][3] * v2[3];
        f32x2 b = b01 + b23;
        ureg[k] = __builtin_amdgcn_rcpf(b.x + b.y);
      }
#pragma unroll
      for (int j2 = 0; j2 < MM2; ++j2) {
        f32x2 s0 = e0c2[j2] * u0      + E2[0][j2] * ureg[0];
        f32x2 s1 = E2[1][j2] * ureg[1] + E2[2][j2] * ureg[2];
        f32x2 s2 = E2[3][j2] * ureg[3] + E2[4][j2] * ureg[4];
        f32x2 s3 = E2[5][j2] * ureg[5] + E2[6][j2] * ureg[6];
        f32x2 s4 = E2[7][j2] * ureg[7];
        f32x2 part = ((s0 + s1) + (s2 + s3)) + s4;
        part.x += __shfl_xor(part.x, 16);
        part.y += __shfl_xor(part.y, 16);
        v2[j2] = mk2(__builtin_amdgcn_rcpf(part.x), __builtin_amdgcn_rcpf(part.y));
      }
    }
    // new row-0 marginal of G (true scale via GS)
#pragma unroll
    for (int j2 = 0; j2 < MM2; ++j2) {
      f32x2 e0u = e0c2[j2] * u0;
      e0u.x += __shfl_xor(e0u.x, 16);
      e0u.y += __shfl_xor(e0u.y, 16);
      g0c[2 * j2]     = GS * v2[j2].x * e0u.x;
      g0c[2 * j2 + 1] = GS * v2[j2].y * e0u.y;
    }
    if (outer < 3) {
      // re-linearize: column factors exp2(+/-C * d(g0 . C2))
      float dg[MM];
#pragma unroll
      for (int j = 0; j < MM; ++j) { dg[j] = g0c[j] - g0p[j]; g0p[j] = g0c[j]; }
      const f32x2* c2p = (const f32x2*)c2l;   // C2_STRIDE even -> 8B aligned
#pragma unroll
      for (int j2 = 0; j2 < MM2; ++j2) {
        f32x2 d01 = dg[0] * c2p[0 * MM2 + j2] + dg[1] * c2p[1 * MM2 + j2];
        f32x2 d23 = dg[2] * c2p[2 * MM2 + j2] + dg[3] * c2p[3 * MM2 + j2];
        f32x2 d45 = dg[4] * c2p[4 * MM2 + j2] + dg[5] * c2p[5 * MM2 + j2];
        f32x2 d67 = dg[6] * c2p[6 * MM2 + j2] + dg[7] * c2p[7 * MM2 + j2];
        f32x2 av = ((d01 + d23) + (d45 + d67)) * C_SCALE;
        e0c2[j2] *= exp2_pk(mk2(-av.x, -av.y));
        f32x2 cfp = exp2_pk(av);
#pragma unroll
        for (int k = 0; k < NNR; ++k) E2[k][j2] *= cfp;
      }
    }
  }

  // ---------------- final fgw = sum G .* (Mh + 0.5*tens(G)) ----------------
  float T0p[MM];
  float tens1 = 0.f;
#pragma unroll
  for (int j = 0; j < MM; ++j) {
    float s = 0.f, cs = 0.f, gd = 0.f;
#pragma unroll
    for (int k = 0; k < MM; ++k) {
      float a = c2l[j * MM + k];
      s += a * a;
      cs += c2l[k * MM + j];
      gd += g0c[k] * c2l[k * MM + j];
    }
    float bq = 0.125f * s;
    T0p[j] = 0.5f * (16.f / 17.f + bq) - 0.125f * cs + gd;    // true T (no QSH)
    float T1p = 0.5f * (1.f / 17.f + bq) - gd;
    tens1 += (0.125f - g0c[j]) * T1p;
  }
  // my regular rows: G[k][j] = GS*u[k]*E[k][j]*v[j]; Mh = hh - pv (re-gather)
  float fgr = 0.f;
#pragma unroll
  for (int k = 0; k < NNR; ++k) {
    int idx = nb[k];
    float4 p0 = Pb[(size_t)idx * 32 + t * 2];
    float4 p1 = Pb[(size_t)idx * 32 + t * 2 + 1];
    float hh = 0.5f * (sqn[idx] + 1.0f);
    f32x2 acc = (E2[k][0] * v2[0]) * (hh - mk2(p0.x, p0.y))
              + (E2[k][1] * v2[1]) * (hh - mk2(p0.z, p0.w))
              + (E2[k][2] * v2[2]) * (hh - mk2(p1.x, p1.y))
              + (E2[k][3] * v2[3]) * (hh - mk2(p1.z, p1.w));
    fgr += ureg[k] * (acc.x + acc.y);
  }
  float fg = GS * fgr;
  {  // lane0-only: center row + structure-constant part over rows>=1
    float4 p0 = Pb[(size_t)node * 32 + t * 2];
    float4 p1 = Pb[(size_t)node * 32 + t * 2 + 1];
    float pv[MM] = {p0.x, p0.y, p0.z, p0.w, p1.x, p1.y, p1.z, p1.w};
    float hh0 = 0.5f * (sqn[node] + 1.0f);
    float r0 = 0.f;
#pragma unroll
    for (int j = 0; j < MM; ++j) r0 += g0c[j] * (hh0 - pv[j] + T0p[j]);
    fg += hmask * (r0 + tens1);
  }
  fg += __shfl_xor(fg, 16);
  if (h == 0) out[node * TT + t] = fg;
}

extern "C" void kernel_launch(void* const* d_in, const int* in_sizes, int n_in,
                              void* d_out, int out_size, void* d_ws, size_t ws_size,
                              hipStream_t stream) {
  const float* x  = (const float*)d_in[0];
  const int*   ei = (const int*)d_in[1];
  const float* tf = (const float*)d_in[2];
  const float* c2 = (const float*)d_in[3];
  const int* dstRow = ei + (in_sizes[1] / 2);   // row 1 of edge_index [2, N*DEG]
  int n_nodes = in_sizes[0] / 64;               // 20000

  float* P   = (float*)d_ws;                    // [n_nodes][128]
  float* sqn = P + (size_t)n_nodes * 128;       // [n_nodes]
  float* out = (float*)d_out;

  int threadsA = (n_nodes / 2) * 16;            // 2 nodes per lane
  precomp<<<(threadsA + 255) / 256, 256, 0, stream>>>(x, tf, P, sqn);
  int lanesB = out_size * 2;                    // 2 lanes per problem
  ltfgw_main<<<(lanesB + 255) / 256, 256, 0, stream>>>(P, sqn, dstRow, c2, out);
}